// Round 5
// baseline (552.317 us; speedup 1.0000x reference)
//
#include <hip/hip_runtime.h>
#include <math.h>

#define N 8192
#define IN_F 256
#define OUT_F 128
#define ALPHA 0.2f

#define SEG 8              // j-segments; grid = 128 row-groups x 8 = 1024 blocks
#define JSEG (N / SEG)     // 1024 columns per wave
#define CHN (JSEG / 32)    // 32 chunks of 32 j per wave

typedef _Float16 f16;
typedef __attribute__((ext_vector_type(4))) float f32x4;
typedef __attribute__((ext_vector_type(8))) _Float16 f16x8;
typedef __attribute__((ext_vector_type(4))) _Float16 f16x4;
typedef __attribute__((ext_vector_type(4))) int i32x4;

// ---------------- Kernel 0: WT[f][k] = (f16) W[k][f] ----------------
__global__ __launch_bounds__(256) void k_prep(const float* __restrict__ W,
                                              f16* __restrict__ WT) {
    int idx = blockIdx.x * 256 + threadIdx.x;   // 128*256 = 32768 elements
    int f = idx >> 8;
    int k = idx & 255;
    WT[idx] = (f16)W[k * OUT_F + f];
}

// ---------------- Kernel 1: Wh = h@W via MFMA; emit WhT(f16), src, dst ----------------
// Block: 256 threads (4 waves), 32 rows. Wave wv handles f-slice [32wv, 32wv+32).
#define HS 280   // f16 row stride for hA: 560 B = 140 dw === 12 (mod 32) -> conflict-optimal b128
__global__ __launch_bounds__(256) void k_wh(const float* __restrict__ h,
                                            const f16* __restrict__ WT,   // [128][256]
                                            const float* __restrict__ a,
                                            f16* __restrict__ WhT,        // [128][8192]
                                            float* __restrict__ src,
                                            float* __restrict__ dst) {
    __shared__ __align__(16) f16 hA[32][HS];       // 17.9 KB
    __shared__ __align__(16) f16 outT[128][40];    // [col][row], 80 B rows, 10 KB
    __shared__ float sred[4][32], dred[4][32];

    const int t = threadIdx.x;
    const int i0 = blockIdx.x * 32;
    const int wv = t >> 6, l = t & 63, ln = l & 15, lq = l >> 4;

    // stage h tile (32 x 256 fp32) -> f16 LDS
    {
        const float4* hg = (const float4*)(h + (size_t)i0 * IN_F);
#pragma unroll
        for (int it = 0; it < 8; ++it) {
            int idx = t + it * 256;        // float4 index, 2048 total
            int r = idx >> 6;
            int c4 = (idx & 63) * 4;
            float4 v = hg[idx];
            f16x4 p = { (f16)v.x, (f16)v.y, (f16)v.z, (f16)v.w };
            *(f16x4*)&hA[r][c4] = p;
        }
    }
    __syncthreads();

    f32x4 acc00 = {0.f,0.f,0.f,0.f}, acc01 = {0.f,0.f,0.f,0.f};
    f32x4 acc10 = {0.f,0.f,0.f,0.f}, acc11 = {0.f,0.f,0.f,0.f};
    const int f0 = 32 * wv;

#pragma unroll
    for (int ks = 0; ks < 8; ++ks) {
        const int k0 = 32 * ks + 8 * lq;
        f16x8 a0 = *(const f16x8*)&hA[ln][k0];
        f16x8 a1 = *(const f16x8*)&hA[16 + ln][k0];
        f16x8 b0 = *(const f16x8*)(WT + (size_t)(f0 + ln) * IN_F + k0);
        f16x8 b1 = *(const f16x8*)(WT + (size_t)(f0 + 16 + ln) * IN_F + k0);
        acc00 = __builtin_amdgcn_mfma_f32_16x16x32_f16(a0, b0, acc00, 0, 0, 0);
        acc01 = __builtin_amdgcn_mfma_f32_16x16x32_f16(a0, b1, acc01, 0, 0, 0);
        acc10 = __builtin_amdgcn_mfma_f32_16x16x32_f16(a1, b0, acc10, 0, 0, 0);
        acc11 = __builtin_amdgcn_mfma_f32_16x16x32_f16(a1, b1, acc11, 0, 0, 0);
    }

    // epilogue: per-lane src/dst partials + outT staging
    const float a1c0 = a[f0 + ln],      a2c0 = a[128 + f0 + ln];
    const float a1c1 = a[f0 + 16 + ln], a2c1 = a[128 + f0 + 16 + ln];
    float sp[8], dp[8];
#pragma unroll
    for (int i = 0; i < 8; ++i) { sp[i] = 0.f; dp[i] = 0.f; }

#pragma unroll
    for (int hh = 0; hh < 2; ++hh) {
        f32x4 v0 = hh ? acc10 : acc00;   // ft=0
        f32x4 v1 = hh ? acc11 : acc01;   // ft=1
        f16x4 p0, p1;
#pragma unroll
        for (int rg = 0; rg < 4; ++rg) {
            sp[hh * 4 + rg] += v0[rg] * a1c0 + v1[rg] * a1c1;
            dp[hh * 4 + rg] += v0[rg] * a2c0 + v1[rg] * a2c1;
            p0[rg] = (f16)v0[rg];
            p1[rg] = (f16)v1[rg];
        }
        *(f16x4*)&outT[f0 + ln][16 * hh + 4 * lq] = p0;
        *(f16x4*)&outT[f0 + 16 + ln][16 * hh + 4 * lq] = p1;
    }
    // reduce over ln (16 lanes sharing lq)
#pragma unroll
    for (int i = 0; i < 8; ++i) {
        float s = sp[i], d = dp[i];
        s += __shfl_down(s, 8, 16); d += __shfl_down(d, 8, 16);
        s += __shfl_down(s, 4, 16); d += __shfl_down(d, 4, 16);
        s += __shfl_down(s, 2, 16); d += __shfl_down(d, 2, 16);
        s += __shfl_down(s, 1, 16); d += __shfl_down(d, 1, 16);
        if (ln == 0) {
            int row = 16 * (i >> 2) + 4 * lq + (i & 3);
            sred[wv][row] = s;
            dred[wv][row] = d;
        }
    }
    __syncthreads();
    if (t < 32) {
        src[i0 + t] = sred[0][t] + sred[1][t] + sred[2][t] + sred[3][t];
        dst[i0 + t] = dred[0][t] + dred[1][t] + dred[2][t] + dred[3][t];
    }
    // write WhT[col][i0..i0+31]
    {
        const int col = t & 127, g = t >> 7;
        f16x8 q0 = *(const f16x8*)&outT[col][16 * g];
        f16x8 q1 = *(const f16x8*)&outT[col][16 * g + 8];
        *(f16x8*)(WhT + (size_t)col * N + i0 + 16 * g) = q0;
        *(f16x8*)(WhT + (size_t)col * N + i0 + 16 * g + 8) = q1;
    }
}

// ---------------- Kernel 2: barrier-free flash attention partials, 16 rows/wave -------
// Grid: 1024 blocks = 128 row-groups x 8 j-segments (s = bid&7). Block: 256 thr = 4 waves.
// Each wave owns 16 rows x 1024 j: HALF the per-wave state of the previous version ->
// ~120 VGPR -> __launch_bounds__(256,4) -> 4 waves/SIMD (2x TLP for latency hiding).
// R1's proven 2-deep ISSUE pipeline; no LDS, no barriers, no fused finalize.
__global__ __launch_bounds__(256, 4) void k_attn(const int* __restrict__ adj,
                                                 const f16* __restrict__ WhT,
                                                 const float* __restrict__ src,
                                                 const float* __restrict__ dst,
                                                 float* __restrict__ part,     // [SEG][N][OUT_F]
                                                 float* __restrict__ lpPart) { // [SEG][N]
    const int t = threadIdx.x;
    const int wv = t >> 6, l = t & 63, ln = l & 15, lq = l >> 4;
    const int bid = blockIdx.x;
    const int s  = bid & (SEG - 1);
    const int rg = bid >> 3;
    const int R0 = rg * 64 + wv * 16;
    const int jb = s * JSEG;

    const float src0 = src[R0 + ln];
    const float csh0 = fabsf(src0) + 4.0f;

    const int*   __restrict__ ar0 = adj + (size_t)(R0 + ln) * N + jb + 8 * lq;
    const float* __restrict__ dp  = dst + jb + 8 * lq;
    const f16*   __restrict__ Bp  = WhT + (size_t)ln * N + jb + 8 * lq;

    f32x4 acc[8];
#pragma unroll
    for (int i = 0; i < 8; ++i) acc[i] = (f32x4){0.f, 0.f, 0.f, 0.f};
    float lp0 = 0.f;

    i32x4 aA0, aA1, aB0, aB1;
    f32x4 dA0, dA1, dB0, dB1;

#define ISSUE(c, A0, A1, D0, D1)                                               \
    {                                                                          \
        const int o = (c) * 32;                                                \
        A0 = __builtin_nontemporal_load((const i32x4*)(ar0 + o));              \
        A1 = __builtin_nontemporal_load((const i32x4*)(ar0 + o + 4));          \
        D0 = *(const f32x4*)(dp + o);                                          \
        D1 = *(const f32x4*)(dp + o + 4);                                      \
    }

    // w computation: leaky_relu via 0.6*e + 0.4*|e| (2 VALU), exp with fixed shift
    auto cw = [&](const i32x4& A0, const i32x4& A1, const f32x4& D0, const f32x4& D1,
                  f16x8& w0) {
#pragma unroll
        for (int k = 0; k < 4; ++k) {
            float e, lk, v;
            e = src0 + D0[k]; lk = fmaf(0.4f, fabsf(e), 0.6f * e);
            v = A0[k] ? __expf(lk - csh0) : 0.f; lp0 += v; w0[k] = (f16)v;
            e = src0 + D1[k]; lk = fmaf(0.4f, fabsf(e), 0.6f * e);
            v = A1[k] ? __expf(lk - csh0) : 0.f; lp0 += v; w0[4 + k] = (f16)v;
        }
    };

    ISSUE(0, aA0, aA1, dA0, dA1);
    ISSUE(1, aB0, aB1, dB0, dB1);

    for (int c = 0; c < CHN; c += 2) {
        {   // even chunk: data in set A
            const f16* bp = Bp + c * 32;
            f16x8 b[8];
#pragma unroll
            for (int ft = 0; ft < 8; ++ft)
                b[ft] = *(const f16x8*)(bp + (size_t)(16 * ft) * N);
            f16x8 w0;
            cw(aA0, aA1, dA0, dA1, w0);
            if (c + 2 < CHN) ISSUE(c + 2, aA0, aA1, dA0, dA1);
#pragma unroll
            for (int ft = 0; ft < 8; ++ft)
                acc[ft] = __builtin_amdgcn_mfma_f32_16x16x32_f16(w0, b[ft], acc[ft], 0, 0, 0);
        }
        {   // odd chunk: data in set B
            const f16* bp = Bp + (c + 1) * 32;
            f16x8 b[8];
#pragma unroll
            for (int ft = 0; ft < 8; ++ft)
                b[ft] = *(const f16x8*)(bp + (size_t)(16 * ft) * N);
            f16x8 w0;
            cw(aB0, aB1, dB0, dB1, w0);
            if (c + 3 < CHN) ISSUE(c + 3, aB0, aB1, dB0, dB1);
#pragma unroll
            for (int ft = 0; ft < 8; ++ft)
                acc[ft] = __builtin_amdgcn_mfma_f32_16x16x32_f16(w0, b[ft], acc[ft], 0, 0, 0);
        }
    }
#undef ISSUE

    // denominator partials: reduce lp over lq (lanes ln, ln+16, ln+32, ln+48)
    lp0 += __shfl_xor(lp0, 16); lp0 += __shfl_xor(lp0, 32);
    if (l < 16) lpPart[(size_t)s * N + R0 + ln] = lp0;

    // numerator partials: C layout col=ln, row=4*lq+reg
    float* __restrict__ pp = part + ((size_t)s * N + R0) * OUT_F;
#pragma unroll
    for (int ft = 0; ft < 8; ++ft)
#pragma unroll
        for (int r = 0; r < 4; ++r)
            pp[(size_t)(4 * lq + r) * OUT_F + 16 * ft + ln] = acc[ft][r];
}

// ---------------- Kernel 3: combine segments, normalize, ELU ----------------
__global__ __launch_bounds__(256) void k_comb(const float* __restrict__ part,
                                              const float* __restrict__ lpPart,
                                              float* __restrict__ out) {
    const int idx = blockIdx.x * 256 + threadIdx.x;   // float4 id, N*OUT_F/4 total
    const int row = idx >> 5;                          // 32 float4 per row
    const int c4  = idx & 31;

    float lsum = 0.f;
#pragma unroll
    for (int s = 0; s < SEG; ++s) lsum += lpPart[(size_t)s * N + row];

    f32x4 v = {0.f, 0.f, 0.f, 0.f};
#pragma unroll
    for (int s = 0; s < SEG; ++s)
        v += *(const f32x4*)(part + ((size_t)s * N + row) * OUT_F + c4 * 4);

    const float inv = 1.0f / lsum;
    f32x4 r;
#pragma unroll
    for (int k = 0; k < 4; ++k) {
        float hp = v[k] * inv;
        r[k] = hp > 0.f ? hp : expm1f(hp);
    }
    *(f32x4*)(out + (size_t)row * OUT_F + c4 * 4) = r;
}

extern "C" void kernel_launch(void* const* d_in, const int* in_sizes, int n_in,
                              void* d_out, int out_size, void* d_ws, size_t ws_size,
                              hipStream_t stream) {
    const float* h   = (const float*)d_in[0];
    const int*   adj = (const int*)d_in[1];
    const float* W   = (const float*)d_in[2];
    const float* a   = (const float*)d_in[3];
    float* out = (float*)d_out;

    f16*   WT  = (f16*)d_ws;                         // 64 KB
    f16*   WhT = (f16*)((char*)d_ws + (1 << 16));    // 2 MB
    float* src = (float*)((char*)WhT + (size_t)OUT_F * N * sizeof(f16));
    float* dst = src + N;
    float* lpP = dst + N;                                  // SEG*N*4 = 256 KB (ends < 8 MB)
    float* part = (float*)((char*)d_ws + (8u << 20));      // SEG*N*OUT_F*4 = 32 MB

    k_prep<<<128, 256, 0, stream>>>(W, WT);
    k_wh<<<N / 32, 256, 0, stream>>>(h, WT, a, WhT, src, dst);
    k_attn<<<(N / 64) * SEG, 256, 0, stream>>>(adj, WhT, src, dst, part, lpP);
    k_comb<<<(N * OUT_F / 4) / 256, 256, 0, stream>>>(part, lpP, out);
}

// Round 6
// 448.198 us; speedup vs baseline: 1.2323x; 1.2323x over previous
//
#include <hip/hip_runtime.h>
#include <math.h>

#define N 8192
#define IN_F 256
#define OUT_F 128
#define ALPHA 0.2f

#define NJC 512            // j-chunk (per-row adj run = 2 KB contiguous)
#define NCH (N / NJC)      // 16 chunks

typedef _Float16 f16;
typedef __attribute__((ext_vector_type(4))) float f32x4;
typedef __attribute__((ext_vector_type(8))) _Float16 f16x8;
typedef __attribute__((ext_vector_type(4))) _Float16 f16x4;
typedef __attribute__((ext_vector_type(4))) int i32x4;

// ---------------- Kernel 0: WT[f][k] = (f16) W[k][f] ----------------
__global__ __launch_bounds__(256) void k_prep(const float* __restrict__ W,
                                              f16* __restrict__ WT) {
    int idx = blockIdx.x * 256 + threadIdx.x;   // 128*256 = 32768 elements
    int f = idx >> 8;
    int k = idx & 255;
    WT[idx] = (f16)W[k * OUT_F + f];
}

// ---------------- Kernel 1: Wh = h@W via MFMA; emit WhT(f16), src, dst ----------------
// Block: 256 threads (4 waves), 32 rows. Wave wv handles f-slice [32wv, 32wv+32).
#define HS 280   // f16 row stride for hA: 560 B = 140 dw === 12 (mod 32) -> conflict-optimal b128
__global__ __launch_bounds__(256) void k_wh(const float* __restrict__ h,
                                            const f16* __restrict__ WT,   // [128][256]
                                            const float* __restrict__ a,
                                            f16* __restrict__ WhT,        // [128][8192]
                                            float* __restrict__ src,
                                            float* __restrict__ dst) {
    __shared__ __align__(16) f16 hA[32][HS];       // 17.9 KB
    __shared__ __align__(16) f16 outT[128][40];    // [col][row], 80 B rows, 10 KB
    __shared__ float sred[4][32], dred[4][32];

    const int t = threadIdx.x;
    const int i0 = blockIdx.x * 32;
    const int wv = t >> 6, l = t & 63, ln = l & 15, lq = l >> 4;

    // stage h tile (32 x 256 fp32) -> f16 LDS
    {
        const float4* hg = (const float4*)(h + (size_t)i0 * IN_F);
#pragma unroll
        for (int it = 0; it < 8; ++it) {
            int idx = t + it * 256;        // float4 index, 2048 total
            int r = idx >> 6;
            int c4 = (idx & 63) * 4;
            float4 v = hg[idx];
            f16x4 p = { (f16)v.x, (f16)v.y, (f16)v.z, (f16)v.w };
            *(f16x4*)&hA[r][c4] = p;
        }
    }
    __syncthreads();

    f32x4 acc00 = {0.f,0.f,0.f,0.f}, acc01 = {0.f,0.f,0.f,0.f};
    f32x4 acc10 = {0.f,0.f,0.f,0.f}, acc11 = {0.f,0.f,0.f,0.f};
    const int f0 = 32 * wv;

#pragma unroll
    for (int ks = 0; ks < 8; ++ks) {
        const int k0 = 32 * ks + 8 * lq;
        f16x8 a0 = *(const f16x8*)&hA[ln][k0];
        f16x8 a1 = *(const f16x8*)&hA[16 + ln][k0];
        f16x8 b0 = *(const f16x8*)(WT + (size_t)(f0 + ln) * IN_F + k0);
        f16x8 b1 = *(const f16x8*)(WT + (size_t)(f0 + 16 + ln) * IN_F + k0);
        acc00 = __builtin_amdgcn_mfma_f32_16x16x32_f16(a0, b0, acc00, 0, 0, 0);
        acc01 = __builtin_amdgcn_mfma_f32_16x16x32_f16(a0, b1, acc01, 0, 0, 0);
        acc10 = __builtin_amdgcn_mfma_f32_16x16x32_f16(a1, b0, acc10, 0, 0, 0);
        acc11 = __builtin_amdgcn_mfma_f32_16x16x32_f16(a1, b1, acc11, 0, 0, 0);
    }

    // epilogue: per-lane src/dst partials + outT staging
    const float a1c0 = a[f0 + ln],      a2c0 = a[128 + f0 + ln];
    const float a1c1 = a[f0 + 16 + ln], a2c1 = a[128 + f0 + 16 + ln];
    float sp[8], dp[8];
#pragma unroll
    for (int i = 0; i < 8; ++i) { sp[i] = 0.f; dp[i] = 0.f; }

#pragma unroll
    for (int hh = 0; hh < 2; ++hh) {
        f32x4 v0 = hh ? acc10 : acc00;   // ft=0
        f32x4 v1 = hh ? acc11 : acc01;   // ft=1
        f16x4 p0, p1;
#pragma unroll
        for (int rg = 0; rg < 4; ++rg) {
            sp[hh * 4 + rg] += v0[rg] * a1c0 + v1[rg] * a1c1;
            dp[hh * 4 + rg] += v0[rg] * a2c0 + v1[rg] * a2c1;
            p0[rg] = (f16)v0[rg];
            p1[rg] = (f16)v1[rg];
        }
        *(f16x4*)&outT[f0 + ln][16 * hh + 4 * lq] = p0;
        *(f16x4*)&outT[f0 + 16 + ln][16 * hh + 4 * lq] = p1;
    }
    // reduce over ln (16 lanes sharing lq)
#pragma unroll
    for (int i = 0; i < 8; ++i) {
        float s = sp[i], d = dp[i];
        s += __shfl_down(s, 8, 16); d += __shfl_down(d, 8, 16);
        s += __shfl_down(s, 4, 16); d += __shfl_down(d, 4, 16);
        s += __shfl_down(s, 2, 16); d += __shfl_down(d, 2, 16);
        s += __shfl_down(s, 1, 16); d += __shfl_down(d, 1, 16);
        if (ln == 0) {
            int row = 16 * (i >> 2) + 4 * lq + (i & 3);
            sred[wv][row] = s;
            dred[wv][row] = d;
        }
    }
    __syncthreads();
    if (t < 32) {
        src[i0 + t] = sred[0][t] + sred[1][t] + sred[2][t] + sred[3][t];
        dst[i0 + t] = dred[0][t] + dred[1][t] + dred[2][t] + dred[3][t];
    }
    // write WhT[col][i0..i0+31]
    {
        const int col = t & 127, g = t >> 7;
        f16x8 q0 = *(const f16x8*)&outT[col][16 * g];
        f16x8 q1 = *(const f16x8*)&outT[col][16 * g + 8];
        *(f16x8*)(WhT + (size_t)col * N + i0 + 16 * g) = q0;
        *(f16x8*)(WhT + (size_t)col * N + i0 + 16 * g + 8) = q1;
    }
}

// ---------------- Kernel 2: fused attention, full rows per block, direct out ----------
// Grid: 512 blocks x 512 threads (8 waves), 2 blocks/CU. Block owns 16 FULL rows:
// adj read exactly once, per-row runs of 2 KB (vs 128 B in the scattered versions),
// plain loads (no NT). Double-buffered row-XOR-swizzled LDS w tile (32 KB).
// Per chunk: ISSUE(c+1) [adj+dst -> regs] -> mpass(c) [16 MFMA/wave, hides HBM lat]
// -> produce(c+1) [exp -> LDS] -> one barrier. Direct out write: no part/comb.
__global__ __launch_bounds__(512, 4) void k_attn(const int* __restrict__ adj,
                                                 const f16* __restrict__ WhT,
                                                 const float* __restrict__ src,
                                                 const float* __restrict__ dst,
                                                 float* __restrict__ out) {
    __shared__ __align__(16) f16 wA[2][16][NJC];   // 32 KB
    __shared__ float lfin[16];

    const int t = threadIdx.x;
    const int wv = t >> 6, l = t & 63, ln = l & 15, lq = l >> 4;
    const int R0 = blockIdx.x * 16;
    const int r0 = 2 * wv, r1 = 2 * wv + 1;        // block-local rows this wave produces

    const float s0 = src[R0 + r0],     s1 = src[R0 + r1];
    const float c0 = fabsf(s0) + 4.f,  c1 = fabsf(s1) + 4.f;

    const int*   __restrict__ a0p = adj + (size_t)(R0 + r0) * N + 4 * l;
    const int*   __restrict__ a1p = adj + (size_t)(R0 + r1) * N + 4 * l;
    const float* __restrict__ dpp = dst + 4 * l;
    const f16*   __restrict__ Bp  = WhT + (size_t)(16 * wv + ln) * N + 8 * lq;

    f32x4 acc = {0.f, 0.f, 0.f, 0.f};
    float lp0 = 0.f, lp1 = 0.f;

    i32x4 A0a, A0b, A1a, A1b;
    f32x4 D0, D1;

    // swizzled LDS byte address: row-XOR on bits 4-6 -> bank-uniform for both the
    // f16x4 producer writes and the f16x8 MFMA-fragment reads (verified mapping)
    char* const wbase = (char*)&wA[0][0][0];
    auto waddr = [&](int buf, int r, int byteInRow) -> char* {
        return wbase + buf * (16 * NJC * 2) + (((r * (NJC * 2)) + byteInRow) ^ ((r & 7) << 4));
    };

#define ISSUE(c)                                                               \
    {                                                                          \
        const int o = (c) * NJC;                                               \
        A0a = *(const i32x4*)(a0p + o);                                        \
        A0b = *(const i32x4*)(a0p + o + 256);                                  \
        A1a = *(const i32x4*)(a1p + o);                                        \
        A1b = *(const i32x4*)(a1p + o + 256);                                  \
        D0  = *(const f32x4*)(dpp + o);                                        \
        D1  = *(const f32x4*)(dpp + o + 256);                                  \
    }

    // leaky_relu via 0.6*e + 0.4*|e|, exp with fixed per-row shift
    auto produce = [&](int c) {
        const int buf = c & 1;
        f16x4 w0a, w0b, w1a, w1b;
#pragma unroll
        for (int k = 0; k < 4; ++k) {
            float e, lk, v;
            e = s0 + D0[k]; lk = fmaf(0.4f, fabsf(e), 0.6f * e);
            v = A0a[k] ? __expf(lk - c0) : 0.f; lp0 += v; w0a[k] = (f16)v;
            e = s0 + D1[k]; lk = fmaf(0.4f, fabsf(e), 0.6f * e);
            v = A0b[k] ? __expf(lk - c0) : 0.f; lp0 += v; w0b[k] = (f16)v;
            e = s1 + D0[k]; lk = fmaf(0.4f, fabsf(e), 0.6f * e);
            v = A1a[k] ? __expf(lk - c1) : 0.f; lp1 += v; w1a[k] = (f16)v;
            e = s1 + D1[k]; lk = fmaf(0.4f, fabsf(e), 0.6f * e);
            v = A1b[k] ? __expf(lk - c1) : 0.f; lp1 += v; w1b[k] = (f16)v;
        }
        *(f16x4*)waddr(buf, r0, 8 * l)       = w0a;   // cols 4l..4l+3
        *(f16x4*)waddr(buf, r0, 8 * l + 512) = w0b;   // cols 256+4l..
        *(f16x4*)waddr(buf, r1, 8 * l)       = w1a;
        *(f16x4*)waddr(buf, r1, 8 * l + 512) = w1b;
    };

    auto mpass = [&](int c) {
        const int buf = c & 1;
        const f16* bp = Bp + c * NJC;
#pragma unroll
        for (int ks = 0; ks < NJC / 32; ++ks) {
            f16x8 b = *(const f16x8*)(bp + 32 * ks);
            f16x8 a = *(const f16x8*)waddr(buf, ln, 64 * ks + 16 * lq);
            acc = __builtin_amdgcn_mfma_f32_16x16x32_f16(a, b, acc, 0, 0, 0);
        }
    };

    ISSUE(0);
    produce(0);
    __syncthreads();

    for (int c = 0; c < NCH; ++c) {
        if (c + 1 < NCH) ISSUE(c + 1);            // HBM loads in flight during mpass
        mpass(c);                                  // reads buf c&1
        if (c + 1 < NCH) produce(c + 1);           // writes buf (c+1)&1
        __syncthreads();
    }
#undef ISSUE

    // softmax denominators: full 64-lane reduce, one value per produced row
#pragma unroll
    for (int off = 32; off; off >>= 1) {
        lp0 += __shfl_xor(lp0, off);
        lp1 += __shfl_xor(lp1, off);
    }
    if (l == 0) { lfin[r0] = lp0; lfin[r1] = lp1; }
    __syncthreads();

    // epilogue: normalize, ELU, direct store (C layout: col=ln -> f, row=4lq+r)
#pragma unroll
    for (int r = 0; r < 4; ++r) {
        const int row = 4 * lq + r;
        float hp = acc[r] / lfin[row];
        float res = hp > 0.f ? hp : expm1f(hp);
        out[(size_t)(R0 + row) * OUT_F + 16 * wv + ln] = res;
    }
}

extern "C" void kernel_launch(void* const* d_in, const int* in_sizes, int n_in,
                              void* d_out, int out_size, void* d_ws, size_t ws_size,
                              hipStream_t stream) {
    const float* h   = (const float*)d_in[0];
    const int*   adj = (const int*)d_in[1];
    const float* W   = (const float*)d_in[2];
    const float* a   = (const float*)d_in[3];
    float* out = (float*)d_out;

    f16*   WT  = (f16*)d_ws;                         // 64 KB
    f16*   WhT = (f16*)((char*)d_ws + (1 << 16));    // 2 MB
    float* src = (float*)((char*)WhT + (size_t)OUT_F * N * sizeof(f16));
    float* dst = src + N;

    k_prep<<<128, 256, 0, stream>>>(W, WT);
    k_wh<<<N / 32, 256, 0, stream>>>(h, WT, a, WhT, src, dst);
    k_attn<<<N / 16, 512, 0, stream>>>(adj, WhT, src, dst, out);
}

// Round 7
// 428.708 us; speedup vs baseline: 1.2883x; 1.0455x over previous
//
#include <hip/hip_runtime.h>
#include <math.h>

#define N 8192
#define IN_F 256
#define OUT_F 128
#define ALPHA 0.2f

typedef _Float16 f16;
typedef __attribute__((ext_vector_type(4))) float f32x4;
typedef __attribute__((ext_vector_type(8))) _Float16 f16x8;
typedef __attribute__((ext_vector_type(4))) _Float16 f16x4;
typedef __attribute__((ext_vector_type(4))) int i32x4;

// ---------------- Kernel 0: WT[f][k] = (f16) W[k][f] ----------------
__global__ __launch_bounds__(256) void k_prep(const float* __restrict__ W,
                                              f16* __restrict__ WT) {
    int idx = blockIdx.x * 256 + threadIdx.x;   // 128*256 = 32768 elements
    int f = idx >> 8;
    int k = idx & 255;
    WT[idx] = (f16)W[k * OUT_F + f];
}

// ---------------- Kernel 1: Wh = h@W via MFMA; emit WhT(f16), src, dst ----------------
// Block: 256 threads (4 waves), 32 rows. Wave wv handles f-slice [32wv, 32wv+32).
#define HS 280   // f16 row stride for hA: 560 B = 140 dw === 12 (mod 32) -> conflict-optimal b128
__global__ __launch_bounds__(256) void k_wh(const float* __restrict__ h,
                                            const f16* __restrict__ WT,   // [128][256]
                                            const float* __restrict__ a,
                                            f16* __restrict__ WhT,        // [128][8192]
                                            float* __restrict__ src,
                                            float* __restrict__ dst) {
    __shared__ __align__(16) f16 hA[32][HS];       // 17.9 KB
    __shared__ __align__(16) f16 outT[128][40];    // [col][row], 80 B rows, 10 KB
    __shared__ float sred[4][32], dred[4][32];

    const int t = threadIdx.x;
    const int i0 = blockIdx.x * 32;
    const int wv = t >> 6, l = t & 63, ln = l & 15, lq = l >> 4;

    // stage h tile (32 x 256 fp32) -> f16 LDS
    {
        const float4* hg = (const float4*)(h + (size_t)i0 * IN_F);
#pragma unroll
        for (int it = 0; it < 8; ++it) {
            int idx = t + it * 256;        // float4 index, 2048 total
            int r = idx >> 6;
            int c4 = (idx & 63) * 4;
            float4 v = hg[idx];
            f16x4 p = { (f16)v.x, (f16)v.y, (f16)v.z, (f16)v.w };
            *(f16x4*)&hA[r][c4] = p;
        }
    }
    __syncthreads();

    f32x4 acc00 = {0.f,0.f,0.f,0.f}, acc01 = {0.f,0.f,0.f,0.f};
    f32x4 acc10 = {0.f,0.f,0.f,0.f}, acc11 = {0.f,0.f,0.f,0.f};
    const int f0 = 32 * wv;

#pragma unroll
    for (int ks = 0; ks < 8; ++ks) {
        const int k0 = 32 * ks + 8 * lq;
        f16x8 a0 = *(const f16x8*)&hA[ln][k0];
        f16x8 a1 = *(const f16x8*)&hA[16 + ln][k0];
        f16x8 b0 = *(const f16x8*)(WT + (size_t)(f0 + ln) * IN_F + k0);
        f16x8 b1 = *(const f16x8*)(WT + (size_t)(f0 + 16 + ln) * IN_F + k0);
        acc00 = __builtin_amdgcn_mfma_f32_16x16x32_f16(a0, b0, acc00, 0, 0, 0);
        acc01 = __builtin_amdgcn_mfma_f32_16x16x32_f16(a0, b1, acc01, 0, 0, 0);
        acc10 = __builtin_amdgcn_mfma_f32_16x16x32_f16(a1, b0, acc10, 0, 0, 0);
        acc11 = __builtin_amdgcn_mfma_f32_16x16x32_f16(a1, b1, acc11, 0, 0, 0);
    }

    // epilogue: per-lane src/dst partials + outT staging
    const float a1c0 = a[f0 + ln],      a2c0 = a[128 + f0 + ln];
    const float a1c1 = a[f0 + 16 + ln], a2c1 = a[128 + f0 + 16 + ln];
    float sp[8], dp[8];
#pragma unroll
    for (int i = 0; i < 8; ++i) { sp[i] = 0.f; dp[i] = 0.f; }

#pragma unroll
    for (int hh = 0; hh < 2; ++hh) {
        f32x4 v0 = hh ? acc10 : acc00;   // ft=0
        f32x4 v1 = hh ? acc11 : acc01;   // ft=1
        f16x4 p0, p1;
#pragma unroll
        for (int rg = 0; rg < 4; ++rg) {
            sp[hh * 4 + rg] += v0[rg] * a1c0 + v1[rg] * a1c1;
            dp[hh * 4 + rg] += v0[rg] * a2c0 + v1[rg] * a2c1;
            p0[rg] = (f16)v0[rg];
            p1[rg] = (f16)v1[rg];
        }
        *(f16x4*)&outT[f0 + ln][16 * hh + 4 * lq] = p0;
        *(f16x4*)&outT[f0 + 16 + ln][16 * hh + 4 * lq] = p1;
    }
    // reduce over ln (16 lanes sharing lq)
#pragma unroll
    for (int i = 0; i < 8; ++i) {
        float s = sp[i], d = dp[i];
        s += __shfl_down(s, 8, 16); d += __shfl_down(d, 8, 16);
        s += __shfl_down(s, 4, 16); d += __shfl_down(d, 4, 16);
        s += __shfl_down(s, 2, 16); d += __shfl_down(d, 2, 16);
        s += __shfl_down(s, 1, 16); d += __shfl_down(d, 1, 16);
        if (ln == 0) {
            int row = 16 * (i >> 2) + 4 * lq + (i & 3);
            sred[wv][row] = s;
            dred[wv][row] = d;
        }
    }
    __syncthreads();
    if (t < 32) {
        src[i0 + t] = sred[0][t] + sred[1][t] + sred[2][t] + sred[3][t];
        dst[i0 + t] = dred[0][t] + dred[1][t] + dred[2][t] + dred[3][t];
    }
    // write WhT[col][i0..i0+31]
    {
        const int col = t & 127, g = t >> 7;
        f16x8 q0 = *(const f16x8*)&outT[col][16 * g];
        f16x8 q1 = *(const f16x8*)&outT[col][16 * g + 8];
        *(f16x8*)(WhT + (size_t)col * N + i0 + 16 * g) = q0;
        *(f16x8*)(WhT + (size_t)col * N + i0 + 16 * g + 8) = q1;
    }
}

// ---------------- Kernel 2: fused masked-softmax attention @ Wh + ELU ----------------
// Block: 512 threads (8 waves), 32 rows. Producer thread t: row pr=t>>4, j-octet pm=t&15.
// Consumer wave wv=t>>6: f-slice [16wv,16wv+16), two 16-row C tiles.
// R0 schedule (best measured: 417.7 us) with nontemporal adj loads: the read-once
// 256 MB stream stays out of L2/L3, minimizing contention with concurrent harness fills.
#define TI 32
#define NJ 128
#define NC (N / NJ)
#define WSTRIDE 152   // f16; 304 B = 76 dw === 12 (mod 32) -> conflict-optimal b128
__global__ __launch_bounds__(512) void k_attn(const int* __restrict__ adj,
                                              const f16* __restrict__ WhT,
                                              const float* __restrict__ src,
                                              const float* __restrict__ dst,
                                              float* __restrict__ out) {
    __shared__ __align__(16) f16 wA[2][TI][WSTRIDE];   // 19456 B
    __shared__ float lfin[TI];

    const int t = threadIdx.x;
    const int i0 = blockIdx.x * TI;
    const int pr = t >> 4;          // 0..31
    const int pm = t & 15;          // 0..15
    const int wv = t >> 6;          // 0..7
    const int l = t & 63, ln = l & 15, lq = l >> 4;

    const float my_src = src[i0 + pr];
    const float cshift = fabsf(my_src) + 4.0f;
    float lp = 0.f;
    f32x4 accv0 = {0.f,0.f,0.f,0.f}, accv1 = {0.f,0.f,0.f,0.f};

    const int* arow = adj + (size_t)(i0 + pr) * N;
    const f16* Bb = WhT + (size_t)(16 * wv + ln) * N + 8 * lq;

    i32x4 aA0, aB0, aA1, aB1;
    float4 dA0, dB0, dA1, dB1;

    auto issue = [&](int c, i32x4& xA, i32x4& xB, float4& xdA, float4& xdB) {
        const int j0 = c * NJ + 8 * pm;
        xA = __builtin_nontemporal_load((const i32x4*)(arow + j0));
        xB = __builtin_nontemporal_load((const i32x4*)(arow + j0 + 4));
        xdA = *(const float4*)(dst + j0);
        xdB = *(const float4*)(dst + j0 + 4);
    };
    auto produce = [&](int c, const i32x4& xA, const i32x4& xB,
                       const float4& xdA, const float4& xdB) {
        float w[8];
        const int*   av = (const int*)&xA;     // [0..3] then xB
        const int*   bv = (const int*)&xB;
        const float* df = (const float*)&xdA;
        const float* ef = (const float*)&xdB;
#pragma unroll
        for (int k = 0; k < 4; ++k) {
            float e = my_src + df[k];
            float lk = e > 0.f ? e : ALPHA * e;
            w[k] = av[k] ? __expf(lk - cshift) : 0.f;
        }
#pragma unroll
        for (int k = 0; k < 4; ++k) {
            float e = my_src + ef[k];
            float lk = e > 0.f ? e : ALPHA * e;
            w[4 + k] = bv[k] ? __expf(lk - cshift) : 0.f;
        }
        f16x8 wp;
#pragma unroll
        for (int k = 0; k < 8; ++k) { lp += w[k]; wp[k] = (f16)w[k]; }
        *(f16x8*)&wA[c & 1][pr][8 * pm] = wp;
    };
    auto mpass = [&](int c) {
        const f16* wb = &wA[c & 1][0][0];
        const f16* bp = Bb + c * NJ;
#pragma unroll
        for (int ks = 0; ks < 4; ++ks) {
            const int k0 = 32 * ks;
            f16x8 bf = *(const f16x8*)(bp + k0);
            f16x8 a0 = *(const f16x8*)(wb + ln * WSTRIDE + k0 + 8 * lq);
            f16x8 a1 = *(const f16x8*)(wb + (16 + ln) * WSTRIDE + k0 + 8 * lq);
            accv0 = __builtin_amdgcn_mfma_f32_16x16x32_f16(a0, bf, accv0, 0, 0, 0);
            accv1 = __builtin_amdgcn_mfma_f32_16x16x32_f16(a1, bf, accv1, 0, 0, 0);
        }
    };

    // prologue: w0 (blocking), then chunk-1 loads in flight
    issue(0, aA0, aB0, dA0, dB0);
    produce(0, aA0, aB0, dA0, dB0);
    issue(1, aA1, aB1, dA1, dB1);
    __syncthreads();

    for (int cc = 0; cc < NC; cc += 2) {
        // chunk cc (even): prefetch cc+2 into slot0, mfma buf0, produce cc+1 from slot1
        if (cc + 2 < NC) issue(cc + 2, aA0, aB0, dA0, dB0);
        mpass(cc);
        produce(cc + 1, aA1, aB1, dA1, dB1);
        __syncthreads();
        // chunk cc+1 (odd): prefetch cc+3 into slot1, mfma buf1, produce cc+2 from slot0
        if (cc + 3 < NC) issue(cc + 3, aA1, aB1, dA1, dB1);
        mpass(cc + 1);
        if (cc + 2 < NC) produce(cc + 2, aA0, aB0, dA0, dB0);
        __syncthreads();
    }

    // softmax denominator: reduce lp over the 16 pm-lanes of each row
    {
        float v = lp;
        v += __shfl_down(v, 8, 16);
        v += __shfl_down(v, 4, 16);
        v += __shfl_down(v, 2, 16);
        v += __shfl_down(v, 1, 16);
        if (pm == 0) lfin[pr] = v;
    }
    __syncthreads();

    // epilogue: normalize, ELU, store (C layout: col=ln, row=4*lq+reg per 16-tile)
#pragma unroll
    for (int hh = 0; hh < 2; ++hh) {
        f32x4 av = hh ? accv1 : accv0;
#pragma unroll
        for (int rg = 0; rg < 4; ++rg) {
            const int row = 16 * hh + 4 * lq + rg;
            float hp = av[rg] / lfin[row];
            float res = hp > 0.f ? hp : expm1f(hp);
            out[(size_t)(i0 + row) * OUT_F + 16 * wv + ln] = res;
        }
    }
}

extern "C" void kernel_launch(void* const* d_in, const int* in_sizes, int n_in,
                              void* d_out, int out_size, void* d_ws, size_t ws_size,
                              hipStream_t stream) {
    const float* h   = (const float*)d_in[0];
    const int*   adj = (const int*)d_in[1];
    const float* W   = (const float*)d_in[2];
    const float* a   = (const float*)d_in[3];
    float* out = (float*)d_out;

    f16*   WT  = (f16*)d_ws;                         // 128*256*2   = 64 KB
    f16*   WhT = (f16*)((char*)d_ws + (1 << 16));    // 128*8192*2  = 2 MB
    float* src = (float*)((char*)WhT + (size_t)OUT_F * N * sizeof(f16));
    float* dst = src + N;

    k_prep<<<128, 256, 0, stream>>>(W, WT);
    k_wh<<<N / 32, 256, 0, stream>>>(h, WT, a, WhT, src, dst);
    k_attn<<<N / TI, 512, 0, stream>>>(adj, WhT, src, dst, out);
}